// Round 9
// baseline (282.358 us; speedup 1.0000x reference)
//
#include <hip/hip_runtime.h>
#include <hip/hip_bf16.h>
#include <math.h>

#define NN 4096
#define IN_F 256
#define OUT_F 64
#define HEADS 4
#define EDGE_F 32
#define HO 256          // HEADS*OUT_F
#define AVEC 160        // 2*OUT_F + EDGE_F
#define ALPHA 0.2f
#define LOG2E 1.44269504088896f

typedef __attribute__((ext_vector_type(8))) short bf16x8;
typedef __attribute__((ext_vector_type(4))) float f32x4;

__device__ __forceinline__ float exp2fast(float x) {
    return __builtin_amdgcn_exp2f(x);       // v_exp_f32: 2^x
}

__device__ __forceinline__ unsigned short f2bf(float x) {
    unsigned u = __float_as_uint(x);
    u += 0x7FFF + ((u >> 16) & 1);          // RNE
    return (unsigned short)(u >> 16);
}

// ---- kernel 1: adj -> transposed bitmask, LDS-staged for coalesced writes ----
// block b: rows i0=b*16..+16. bits[jw][ii] in LDS, then 64B-segment writeout.
__global__ __launch_bounds__(256) void k_pack(const int* __restrict__ adj,
                                              unsigned* __restrict__ abitsT) {
    __shared__ unsigned bits[128][16];      // 8 KB
    const int tid = threadIdx.x;
    const int w = tid >> 6, l = tid & 63;
    const int i0 = blockIdx.x * 16;
    for (int ii = 0; ii < 16; ++ii) {
        const int* row = adj + (size_t)(i0 + ii) * NN + w * 1024;
#pragma unroll
        for (int r = 0; r < 16; ++r) {
            const unsigned long long m = __ballot(row[r * 64 + l] > 0);
            const int jw = w * 32 + r * 2;
            if (l == 0) bits[jw][ii] = (unsigned)m;
            else if (l == 1) bits[jw + 1][ii] = (unsigned)(m >> 32);
        }
    }
    __syncthreads();
    // writeout: 2048 dwords; each 16-thread group = one 64B contiguous segment
#pragma unroll
    for (int t = tid; t < 128 * 16; t += 256) {
        const int jw = t >> 4, ii = t & 15;
        abitsT[(size_t)jw * NN + i0 + ii] = bits[jw][ii];
    }
}

// ---- kernel 2: Wh GEMM -> pk (pre-packed bf16 B-fragments); fused coeffs ----
// block = (jb, hd): rows n0=jb*32, cols hd*64..+64.
// pk fragment layout: pk[((jblk*HEADS+hd)*4+g)*512 + lane*8 + e],
//   lane=kb*16+lr holds Whb[hd*64+g*16+lr][jblk*32+kb*8+e]  (B-frag of mfma_16x16x32_bf16)
__global__ __launch_bounds__(256) void k_wh(const float* __restrict__ h,
                                            const float* __restrict__ W,
                                            const float* __restrict__ a,
                                            const float* __restrict__ edge_attr,
                                            unsigned short* __restrict__ pk,
                                            float* __restrict__ src,
                                            float* __restrict__ cdpT) {
    __shared__ float hs[32][32];
    __shared__ float Ws[32][64];
    const int tid = threadIdx.x;
    const int jb = blockIdx.x >> 2, hd = blockIdx.x & 3;
    const int n0 = jb * 32;
    const int rg = tid >> 6, cl = tid & 63;
    float acc[8];
#pragma unroll
    for (int r = 0; r < 8; ++r) acc[r] = 0.f;

    for (int kc = 0; kc < IN_F; kc += 32) {
        {   // stage h tile: 32 rows x 32 k
            const int r = tid >> 3, k4 = (tid & 7) << 2;
            *(float4*)&hs[r][k4] = *(const float4*)&h[(size_t)(n0 + r) * IN_F + kc + k4];
        }
#pragma unroll
        for (int q = 0; q < 2; ++q) {   // stage W tile: 32 k x 64 c
            const int f = tid + q * 256;
            const int k = f >> 4, c4 = (f & 15) << 2;
            *(float4*)&Ws[k][c4] = *(const float4*)&W[(size_t)(kc + k) * HO + hd * 64 + c4];
        }
        __syncthreads();
#pragma unroll
        for (int k = 0; k < 32; ++k) {
            const float wv = Ws[k][cl];
#pragma unroll
            for (int r = 0; r < 8; ++r)
                acc[r] = fmaf(hs[rg * 8 + r][k], wv, acc[r]);
        }
        __syncthreads();
    }

    // pk store: one bf16x8 fragment per thread (kb = rg, e = r)
    {
        const int g = cl >> 4, lr = cl & 15;
        unsigned short* fb = pk + ((size_t)(jb * HEADS + hd) * 4 + g) * 512;
        bf16x8 v;
#pragma unroll
        for (int r = 0; r < 8; ++r) v[r] = (short)f2bf(acc[r]);
        *(bf16x8*)(fb + (rg * 16 + lr) * 8) = v;
    }

    // fused coeffs: this block's 64 cols ARE head hd's features -> full dots
    const float asrc = a[hd * AVEC + cl];
    const float adst = a[hd * AVEC + OUT_F + cl];
    float s_keep = 0.f, d_keep = 0.f;
#pragma unroll
    for (int r = 0; r < 8; ++r) {
        float sp = acc[r] * asrc;
        float dp = acc[r] * adst;
#pragma unroll
        for (int off = 32; off >= 1; off >>= 1) {
            sp += __shfl_xor(sp, off);
            dp += __shfl_xor(dp, off);
        }
        if (cl == r) { s_keep = sp; d_keep = dp; }
    }
    if (cl < 8) {
        const int i = n0 + rg * 8 + cl;
        float eg = 0.f;
        const float* erow = edge_attr + (size_t)i * EDGE_F;
#pragma unroll
        for (int e4 = 0; e4 < EDGE_F; e4 += 4) {
            const float4 ev = *(const float4*)(erow + e4);
            const float4 av = *(const float4*)(a + hd * AVEC + 2 * OUT_F + e4);
            eg = fmaf(ev.x, av.x, fmaf(ev.y, av.y, fmaf(ev.z, av.z, fmaf(ev.w, av.w, eg))));
        }
        src[i * HEADS + hd] = s_keep * LOG2E;                  // pre-scaled for exp2
        cdpT[(size_t)hd * NN + i] = (d_keep + eg) * LOG2E;
    }
}

// ---- kernel 3: PV via MFMA, full J per block, L via ones-MFMA, LDS reduce, fused ELU ----
// block = (ib, hd): rows i0=ib*32, head hd. 8 waves: js = w&3 (j-slice), mt = w>>2 (m-tile).
__global__ __launch_bounds__(512, 4) void k_pv(const unsigned* __restrict__ abitsT,
                                               const unsigned short* __restrict__ pk,
                                               const float* __restrict__ src,
                                               const float* __restrict__ cdpT,
                                               float* __restrict__ out) {
    __shared__ float plds[4][32][65];   // [js][row][col] partial C
    __shared__ float lsum[4][32];       // [js][row] partial L
    const int tid = threadIdx.x;
    const int w = tid >> 6, l = tid & 63;
    const int js = w & 3, mt = w >> 2;
    const int ib = blockIdx.x >> 2, hd = blockIdx.x & 3;
    const int i0 = ib * 32;
    const int lr = l & 15, kb = l >> 4;
    const int i = i0 + mt * 16 + lr;                 // this lane's A-row
    const float si = src[i * HEADS + hd];
    const float* crow = cdpT + (size_t)hd * NN + kb * 8;
    const unsigned short* pkb = pk + (size_t)hd * 2048 + l * 8;

    bf16x8 bones;
#pragma unroll
    for (int r = 0; r < 8; ++r) bones[r] = (short)0x3F80;   // bf16 1.0

    f32x4 acc0 = {0.f, 0.f, 0.f, 0.f};
    f32x4 acc1 = {0.f, 0.f, 0.f, 0.f};
    f32x4 acc2 = {0.f, 0.f, 0.f, 0.f};
    f32x4 acc3 = {0.f, 0.f, 0.f, 0.f};
    f32x4 accL = {0.f, 0.f, 0.f, 0.f};

    for (int jt = js * 32; jt < NN; jt += 128) {
        const unsigned wbits = abitsT[(size_t)(jt >> 5) * NN + i];
        const unsigned byte = (wbits >> (kb * 8)) & 0xFFu;
        const float4 c0 = *(const float4*)(crow + jt);
        const float4 c1 = *(const float4*)(crow + jt + 4);
        const unsigned short* fb = pkb + (size_t)(jt >> 5) * (HEADS * 4 * 512);
        const bf16x8 b0 = *(const bf16x8*)(fb);
        const bf16x8 b1 = *(const bf16x8*)(fb + 512);
        const bf16x8 b2 = *(const bf16x8*)(fb + 1024);
        const bf16x8 b3 = *(const bf16x8*)(fb + 1536);
        float e, p0, p1, p2, p3, p4, p5, p6, p7;
        e = si + c0.x; e = fmaxf(e, ALPHA * e); e = (byte &   1u) ? e : 0.f; p0 = exp2fast(e);
        e = si + c0.y; e = fmaxf(e, ALPHA * e); e = (byte &   2u) ? e : 0.f; p1 = exp2fast(e);
        e = si + c0.z; e = fmaxf(e, ALPHA * e); e = (byte &   4u) ? e : 0.f; p2 = exp2fast(e);
        e = si + c0.w; e = fmaxf(e, ALPHA * e); e = (byte &   8u) ? e : 0.f; p3 = exp2fast(e);
        e = si + c1.x; e = fmaxf(e, ALPHA * e); e = (byte &  16u) ? e : 0.f; p4 = exp2fast(e);
        e = si + c1.y; e = fmaxf(e, ALPHA * e); e = (byte &  32u) ? e : 0.f; p5 = exp2fast(e);
        e = si + c1.z; e = fmaxf(e, ALPHA * e); e = (byte &  64u) ? e : 0.f; p6 = exp2fast(e);
        e = si + c1.w; e = fmaxf(e, ALPHA * e); e = (byte & 128u) ? e : 0.f; p7 = exp2fast(e);
        bf16x8 af;
        af[0] = (short)f2bf(p0); af[1] = (short)f2bf(p1);
        af[2] = (short)f2bf(p2); af[3] = (short)f2bf(p3);
        af[4] = (short)f2bf(p4); af[5] = (short)f2bf(p5);
        af[6] = (short)f2bf(p6); af[7] = (short)f2bf(p7);
        acc0 = __builtin_amdgcn_mfma_f32_16x16x32_bf16(af, b0, acc0, 0, 0, 0);
        acc1 = __builtin_amdgcn_mfma_f32_16x16x32_bf16(af, b1, acc1, 0, 0, 0);
        acc2 = __builtin_amdgcn_mfma_f32_16x16x32_bf16(af, b2, acc2, 0, 0, 0);
        acc3 = __builtin_amdgcn_mfma_f32_16x16x32_bf16(af, b3, acc3, 0, 0, 0);
        accL = __builtin_amdgcn_mfma_f32_16x16x32_bf16(af, bones, accL, 0, 0, 0);
    }

    // L partials: accL[r] = row-sum for row kb*4+r (same across all 16 cols)
    if (lr == 0) {
#pragma unroll
        for (int r = 0; r < 4; ++r)
            lsum[js][mt * 16 + kb * 4 + r] = accL[r];
    }
    // C partials: row = mt*16 + kb*4 + r, col = g*16 + lr
#pragma unroll
    for (int r = 0; r < 4; ++r) {
        const int row = mt * 16 + kb * 4 + r;
        plds[js][row][ 0 + lr] = acc0[r];
        plds[js][row][16 + lr] = acc1[r];
        plds[js][row][32 + lr] = acc2[r];
        plds[js][row][48 + lr] = acc3[r];
    }
    __syncthreads();

    // cross-wave reduce + divide + ELU + store (2048 elems, 4 per thread)
    const int row = tid >> 4, c4 = (tid & 15) << 2;
    const float L = lsum[0][row] + lsum[1][row] + lsum[2][row] + lsum[3][row];
    const float inv = 1.f / L;
    float4 o;
    float x;
    x = (plds[0][row][c4 + 0] + plds[1][row][c4 + 0] + plds[2][row][c4 + 0] + plds[3][row][c4 + 0]) * inv;
    o.x = x > 0.f ? x : (__expf(x) - 1.f);
    x = (plds[0][row][c4 + 1] + plds[1][row][c4 + 1] + plds[2][row][c4 + 1] + plds[3][row][c4 + 1]) * inv;
    o.y = x > 0.f ? x : (__expf(x) - 1.f);
    x = (plds[0][row][c4 + 2] + plds[1][row][c4 + 2] + plds[2][row][c4 + 2] + plds[3][row][c4 + 2]) * inv;
    o.z = x > 0.f ? x : (__expf(x) - 1.f);
    x = (plds[0][row][c4 + 3] + plds[1][row][c4 + 3] + plds[2][row][c4 + 3] + plds[3][row][c4 + 3]) * inv;
    o.w = x > 0.f ? x : (__expf(x) - 1.f);
    *(float4*)(out + (size_t)(i0 + row) * HO + hd * 64 + c4) = o;
}

extern "C" void kernel_launch(void* const* d_in, const int* in_sizes, int n_in,
                              void* d_out, int out_size, void* d_ws, size_t ws_size,
                              hipStream_t stream) {
    const float* h         = (const float*)d_in[0];
    const int*   adj       = (const int*)d_in[1];
    const float* edge_attr = (const float*)d_in[2];
    const float* W         = (const float*)d_in[3];
    const float* a         = (const float*)d_in[4];
    float* out = (float*)d_out;

    unsigned short* pk     = (unsigned short*)d_ws;                 // NN*HO bf16 (2 MB)
    float*          cdpT   = (float*)(pk + (size_t)NN * HO);        // HEADS*NN f32
    float*          src    = cdpT + (size_t)HEADS * NN;             // NN*HEADS f32
    unsigned*       abitsT = (unsigned*)(src + (size_t)NN * HEADS); // NN*NN/32 (2 MB)

    k_pack<<<NN / 16, 256, 0, stream>>>(adj, abitsT);
    k_wh<<<128 * HEADS, 256, 0, stream>>>(h, W, a, edge_attr, pk, src, cdpT);
    k_pv<<<128 * HEADS, 512, 0, stream>>>(abitsT, pk, src, cdpT, out);
}

// Round 10
// 173.383 us; speedup vs baseline: 1.6285x; 1.6285x over previous
//
#include <hip/hip_runtime.h>
#include <hip/hip_bf16.h>
#include <math.h>

#define NN 4096
#define IN_F 256
#define OUT_F 64
#define HEADS 4
#define EDGE_F 32
#define HO 256          // HEADS*OUT_F
#define AVEC 160        // 2*OUT_F + EDGE_F
#define ALPHA 0.2f
#define LOG2E 1.44269504088896f

typedef __attribute__((ext_vector_type(8))) short bf16x8;
typedef __attribute__((ext_vector_type(4))) float f32x4;

__device__ __forceinline__ float exp2fast(float x) {
    return __builtin_amdgcn_exp2f(x);       // v_exp_f32: 2^x
}

__device__ __forceinline__ unsigned short f2bf(float x) {
    unsigned u = __float_as_uint(x);
    u += 0x7FFF + ((u >> 16) & 1);          // RNE
    return (unsigned short)(u >> 16);
}

// ---- kernel 1: adj -> transposed bitmask; staged writes + high occupancy/ILP ----
// block = (ib, js): rows i0=ib*16..+16, j in [js*1024, js*1024+1024).
// wave w covers j-subrange w*256..+256 (4 r-groups of 64 lanes).
// Batched loads (32 in flight) -> ballots -> LDS bits[32][16] -> coalesced writeout.
__global__ __launch_bounds__(256) void k_pack(const int* __restrict__ adj,
                                              unsigned* __restrict__ abitsT) {
    __shared__ unsigned bits[32][16];       // 2 KB: [jw_local][ii]
    const int tid = threadIdx.x;
    const int w = tid >> 6, l = tid & 63;
    const int ib = blockIdx.x >> 2, js = blockIdx.x & 3;
    const int i0 = ib * 16;
    const int jbase = js * 1024 + w * 256;
    const int* base = adj + (size_t)i0 * NN + jbase + l;

#pragma unroll
    for (int half = 0; half < 2; ++half) {
        int vv[32];
#pragma unroll
        for (int t = 0; t < 32; ++t) {
            const int ii = (t & 7) + half * 8;      // 8 rows per half
            const int r = t >> 3;                   // 4 j-groups
            vv[t] = base[(size_t)ii * NN + r * 64];
        }
#pragma unroll
        for (int t = 0; t < 32; ++t) {
            const int ii = (t & 7) + half * 8;
            const int r = t >> 3;
            const unsigned long long m = __ballot(vv[t] > 0);
            const int jwl = w * 8 + r * 2;
            if (l == 0) bits[jwl][ii] = (unsigned)m;
            else if (l == 1) bits[jwl + 1][ii] = (unsigned)(m >> 32);
        }
    }
    __syncthreads();
    // writeout: 32 jw x 16 ii = 512 dwords; 16-thread groups = 64B segments
#pragma unroll
    for (int t = tid; t < 32 * 16; t += 256) {
        const int jwl = t >> 4, ii = t & 15;
        abitsT[(size_t)(js * 32 + jwl) * NN + i0 + ii] = bits[jwl][ii];
    }
}

// ---- kernel 2: Wh GEMM -> pk (pre-packed bf16 B-fragments); fused coeffs ----
// block = (jb, hd): rows n0=jb*32, cols hd*64..+64.
// pk fragment layout: pk[((jblk*HEADS+hd)*4+g)*512 + lane*8 + e],
//   lane=kb*16+lr holds Whb[hd*64+g*16+lr][jblk*32+kb*8+e]  (B-frag of mfma_16x16x32_bf16)
__global__ __launch_bounds__(256) void k_wh(const float* __restrict__ h,
                                            const float* __restrict__ W,
                                            const float* __restrict__ a,
                                            const float* __restrict__ edge_attr,
                                            unsigned short* __restrict__ pk,
                                            float* __restrict__ src,
                                            float* __restrict__ cdpT) {
    __shared__ float hs[32][32];
    __shared__ float Ws[32][64];
    const int tid = threadIdx.x;
    const int jb = blockIdx.x >> 2, hd = blockIdx.x & 3;
    const int n0 = jb * 32;
    const int rg = tid >> 6, cl = tid & 63;
    float acc[8];
#pragma unroll
    for (int r = 0; r < 8; ++r) acc[r] = 0.f;

    for (int kc = 0; kc < IN_F; kc += 32) {
        {   // stage h tile: 32 rows x 32 k
            const int r = tid >> 3, k4 = (tid & 7) << 2;
            *(float4*)&hs[r][k4] = *(const float4*)&h[(size_t)(n0 + r) * IN_F + kc + k4];
        }
#pragma unroll
        for (int q = 0; q < 2; ++q) {   // stage W tile: 32 k x 64 c
            const int f = tid + q * 256;
            const int k = f >> 4, c4 = (f & 15) << 2;
            *(float4*)&Ws[k][c4] = *(const float4*)&W[(size_t)(kc + k) * HO + hd * 64 + c4];
        }
        __syncthreads();
#pragma unroll
        for (int k = 0; k < 32; ++k) {
            const float wv = Ws[k][cl];
#pragma unroll
            for (int r = 0; r < 8; ++r)
                acc[r] = fmaf(hs[rg * 8 + r][k], wv, acc[r]);
        }
        __syncthreads();
    }

    // pk store: one bf16x8 fragment per thread (kb = rg, e = r)
    {
        const int g = cl >> 4, lr = cl & 15;
        unsigned short* fb = pk + ((size_t)(jb * HEADS + hd) * 4 + g) * 512;
        bf16x8 v;
#pragma unroll
        for (int r = 0; r < 8; ++r) v[r] = (short)f2bf(acc[r]);
        *(bf16x8*)(fb + (rg * 16 + lr) * 8) = v;
    }

    // fused coeffs: this block's 64 cols ARE head hd's features -> full dots
    const float asrc = a[hd * AVEC + cl];
    const float adst = a[hd * AVEC + OUT_F + cl];
    float s_keep = 0.f, d_keep = 0.f;
#pragma unroll
    for (int r = 0; r < 8; ++r) {
        float sp = acc[r] * asrc;
        float dp = acc[r] * adst;
#pragma unroll
        for (int off = 32; off >= 1; off >>= 1) {
            sp += __shfl_xor(sp, off);
            dp += __shfl_xor(dp, off);
        }
        if (cl == r) { s_keep = sp; d_keep = dp; }
    }
    if (cl < 8) {
        const int i = n0 + rg * 8 + cl;
        float eg = 0.f;
        const float* erow = edge_attr + (size_t)i * EDGE_F;
#pragma unroll
        for (int e4 = 0; e4 < EDGE_F; e4 += 4) {
            const float4 ev = *(const float4*)(erow + e4);
            const float4 av = *(const float4*)(a + hd * AVEC + 2 * OUT_F + e4);
            eg = fmaf(ev.x, av.x, fmaf(ev.y, av.y, fmaf(ev.z, av.z, fmaf(ev.w, av.w, eg))));
        }
        src[i * HEADS + hd] = s_keep * LOG2E;                  // pre-scaled for exp2
        cdpT[(size_t)hd * NN + i] = (d_keep + eg) * LOG2E;
    }
}

// ---- kernel 3: PV via MFMA, full J per block, L via ones-MFMA, LDS reduce, fused ELU ----
// block = (ib, hd): rows i0=ib*32, head hd. 8 waves: js = w&3 (j-slice), mt = w>>2 (m-tile).
__global__ __launch_bounds__(512, 4) void k_pv(const unsigned* __restrict__ abitsT,
                                               const unsigned short* __restrict__ pk,
                                               const float* __restrict__ src,
                                               const float* __restrict__ cdpT,
                                               float* __restrict__ out) {
    __shared__ float plds[4][32][65];   // [js][row][col] partial C
    __shared__ float lsum[4][32];       // [js][row] partial L
    const int tid = threadIdx.x;
    const int w = tid >> 6, l = tid & 63;
    const int js = w & 3, mt = w >> 2;
    const int ib = blockIdx.x >> 2, hd = blockIdx.x & 3;
    const int i0 = ib * 32;
    const int lr = l & 15, kb = l >> 4;
    const int i = i0 + mt * 16 + lr;                 // this lane's A-row
    const float si = src[i * HEADS + hd];
    const float* crow = cdpT + (size_t)hd * NN + kb * 8;
    const unsigned short* pkb = pk + (size_t)hd * 2048 + l * 8;

    bf16x8 bones;
#pragma unroll
    for (int r = 0; r < 8; ++r) bones[r] = (short)0x3F80;   // bf16 1.0

    f32x4 acc0 = {0.f, 0.f, 0.f, 0.f};
    f32x4 acc1 = {0.f, 0.f, 0.f, 0.f};
    f32x4 acc2 = {0.f, 0.f, 0.f, 0.f};
    f32x4 acc3 = {0.f, 0.f, 0.f, 0.f};
    f32x4 accL = {0.f, 0.f, 0.f, 0.f};

    for (int jt = js * 32; jt < NN; jt += 128) {
        const unsigned wbits = abitsT[(size_t)(jt >> 5) * NN + i];
        const unsigned byte = (wbits >> (kb * 8)) & 0xFFu;
        const float4 c0 = *(const float4*)(crow + jt);
        const float4 c1 = *(const float4*)(crow + jt + 4);
        const unsigned short* fb = pkb + (size_t)(jt >> 5) * (HEADS * 4 * 512);
        const bf16x8 b0 = *(const bf16x8*)(fb);
        const bf16x8 b1 = *(const bf16x8*)(fb + 512);
        const bf16x8 b2 = *(const bf16x8*)(fb + 1024);
        const bf16x8 b3 = *(const bf16x8*)(fb + 1536);
        float e, p0, p1, p2, p3, p4, p5, p6, p7;
        e = si + c0.x; e = fmaxf(e, ALPHA * e); e = (byte &   1u) ? e : 0.f; p0 = exp2fast(e);
        e = si + c0.y; e = fmaxf(e, ALPHA * e); e = (byte &   2u) ? e : 0.f; p1 = exp2fast(e);
        e = si + c0.z; e = fmaxf(e, ALPHA * e); e = (byte &   4u) ? e : 0.f; p2 = exp2fast(e);
        e = si + c0.w; e = fmaxf(e, ALPHA * e); e = (byte &   8u) ? e : 0.f; p3 = exp2fast(e);
        e = si + c1.x; e = fmaxf(e, ALPHA * e); e = (byte &  16u) ? e : 0.f; p4 = exp2fast(e);
        e = si + c1.y; e = fmaxf(e, ALPHA * e); e = (byte &  32u) ? e : 0.f; p5 = exp2fast(e);
        e = si + c1.z; e = fmaxf(e, ALPHA * e); e = (byte &  64u) ? e : 0.f; p6 = exp2fast(e);
        e = si + c1.w; e = fmaxf(e, ALPHA * e); e = (byte & 128u) ? e : 0.f; p7 = exp2fast(e);
        bf16x8 af;
        af[0] = (short)f2bf(p0); af[1] = (short)f2bf(p1);
        af[2] = (short)f2bf(p2); af[3] = (short)f2bf(p3);
        af[4] = (short)f2bf(p4); af[5] = (short)f2bf(p5);
        af[6] = (short)f2bf(p6); af[7] = (short)f2bf(p7);
        acc0 = __builtin_amdgcn_mfma_f32_16x16x32_bf16(af, b0, acc0, 0, 0, 0);
        acc1 = __builtin_amdgcn_mfma_f32_16x16x32_bf16(af, b1, acc1, 0, 0, 0);
        acc2 = __builtin_amdgcn_mfma_f32_16x16x32_bf16(af, b2, acc2, 0, 0, 0);
        acc3 = __builtin_amdgcn_mfma_f32_16x16x32_bf16(af, b3, acc3, 0, 0, 0);
        accL = __builtin_amdgcn_mfma_f32_16x16x32_bf16(af, bones, accL, 0, 0, 0);
    }

    // L partials: accL[r] = row-sum for row kb*4+r (same across all 16 cols)
    if (lr == 0) {
#pragma unroll
        for (int r = 0; r < 4; ++r)
            lsum[js][mt * 16 + kb * 4 + r] = accL[r];
    }
    // C partials: row = mt*16 + kb*4 + r, col = g*16 + lr
#pragma unroll
    for (int r = 0; r < 4; ++r) {
        const int row = mt * 16 + kb * 4 + r;
        plds[js][row][ 0 + lr] = acc0[r];
        plds[js][row][16 + lr] = acc1[r];
        plds[js][row][32 + lr] = acc2[r];
        plds[js][row][48 + lr] = acc3[r];
    }
    __syncthreads();

    // cross-wave reduce + divide + ELU + store (2048 elems, 4 per thread)
    const int row = tid >> 4, c4 = (tid & 15) << 2;
    const float L = lsum[0][row] + lsum[1][row] + lsum[2][row] + lsum[3][row];
    const float inv = 1.f / L;
    float4 o;
    float x;
    x = (plds[0][row][c4 + 0] + plds[1][row][c4 + 0] + plds[2][row][c4 + 0] + plds[3][row][c4 + 0]) * inv;
    o.x = x > 0.f ? x : (__expf(x) - 1.f);
    x = (plds[0][row][c4 + 1] + plds[1][row][c4 + 1] + plds[2][row][c4 + 1] + plds[3][row][c4 + 1]) * inv;
    o.y = x > 0.f ? x : (__expf(x) - 1.f);
    x = (plds[0][row][c4 + 2] + plds[1][row][c4 + 2] + plds[2][row][c4 + 2] + plds[3][row][c4 + 2]) * inv;
    o.z = x > 0.f ? x : (__expf(x) - 1.f);
    x = (plds[0][row][c4 + 3] + plds[1][row][c4 + 3] + plds[2][row][c4 + 3] + plds[3][row][c4 + 3]) * inv;
    o.w = x > 0.f ? x : (__expf(x) - 1.f);
    *(float4*)(out + (size_t)(i0 + row) * HO + hd * 64 + c4) = o;
}

extern "C" void kernel_launch(void* const* d_in, const int* in_sizes, int n_in,
                              void* d_out, int out_size, void* d_ws, size_t ws_size,
                              hipStream_t stream) {
    const float* h         = (const float*)d_in[0];
    const int*   adj       = (const int*)d_in[1];
    const float* edge_attr = (const float*)d_in[2];
    const float* W         = (const float*)d_in[3];
    const float* a         = (const float*)d_in[4];
    float* out = (float*)d_out;

    unsigned short* pk     = (unsigned short*)d_ws;                 // NN*HO bf16 (2 MB)
    float*          cdpT   = (float*)(pk + (size_t)NN * HO);        // HEADS*NN f32
    float*          src    = cdpT + (size_t)HEADS * NN;             // NN*HEADS f32
    unsigned*       abitsT = (unsigned*)(src + (size_t)NN * HEADS); // NN*NN/32 (2 MB)

    k_pack<<<256 * 4, 256, 0, stream>>>(adj, abitsT);
    k_wh<<<128 * HEADS, 256, 0, stream>>>(h, W, a, edge_attr, pk, src, cdpT);
    k_pv<<<128 * HEADS, 512, 0, stream>>>(abitsT, pk, src, cdpT, out);
}

// Round 11
// 157.593 us; speedup vs baseline: 1.7917x; 1.1002x over previous
//
#include <hip/hip_runtime.h>
#include <hip/hip_bf16.h>
#include <math.h>

#define NN 4096
#define IN_F 256
#define OUT_F 64
#define HEADS 4
#define EDGE_F 32
#define HO 256          // HEADS*OUT_F
#define AVEC 160        // 2*OUT_F + EDGE_F
#define ALPHA 0.2f
#define LOG2E 1.44269504088896f

typedef __attribute__((ext_vector_type(8))) short bf16x8;
typedef __attribute__((ext_vector_type(4))) float f32x4;

__device__ __forceinline__ float exp2fast(float x) {
    return __builtin_amdgcn_exp2f(x);       // v_exp_f32: 2^x
}

__device__ __forceinline__ unsigned short f2bf(float x) {
    unsigned u = __float_as_uint(x);
    u += 0x7FFF + ((u >> 16) & 1);          // RNE
    return (unsigned short)(u >> 16);
}

// ---- kernel 1: adj -> transposed bitmask; staged writes + high occupancy/ILP ----
__global__ __launch_bounds__(256) void k_pack(const int* __restrict__ adj,
                                              unsigned* __restrict__ abitsT) {
    __shared__ unsigned bits[32][16];       // 2 KB: [jw_local][ii]
    const int tid = threadIdx.x;
    const int w = tid >> 6, l = tid & 63;
    const int ib = blockIdx.x >> 2, js = blockIdx.x & 3;
    const int i0 = ib * 16;
    const int jbase = js * 1024 + w * 256;
    const int* base = adj + (size_t)i0 * NN + jbase + l;

#pragma unroll
    for (int half = 0; half < 2; ++half) {
        int vv[32];
#pragma unroll
        for (int t = 0; t < 32; ++t) {
            const int ii = (t & 7) + half * 8;      // 8 rows per half
            const int r = t >> 3;                   // 4 j-groups
            vv[t] = base[(size_t)ii * NN + r * 64];
        }
#pragma unroll
        for (int t = 0; t < 32; ++t) {
            const int ii = (t & 7) + half * 8;
            const int r = t >> 3;
            const unsigned long long m = __ballot(vv[t] > 0);
            const int jwl = w * 8 + r * 2;
            if (l == 0) bits[jwl][ii] = (unsigned)m;
            else if (l == 1) bits[jwl + 1][ii] = (unsigned)(m >> 32);
        }
    }
    __syncthreads();
#pragma unroll
    for (int t = tid; t < 32 * 16; t += 256) {
        const int jwl = t >> 4, ii = t & 15;
        abitsT[(size_t)(js * 32 + jwl) * NN + i0 + ii] = bits[jwl][ii];
    }
}

// ---- kernel 2: Wh GEMM -> pk (pre-packed bf16 B-fragments); fused coeffs ----
__global__ __launch_bounds__(256) void k_wh(const float* __restrict__ h,
                                            const float* __restrict__ W,
                                            const float* __restrict__ a,
                                            const float* __restrict__ edge_attr,
                                            unsigned short* __restrict__ pk,
                                            float* __restrict__ src,
                                            float* __restrict__ cdpT) {
    __shared__ float hs[32][32];
    __shared__ float Ws[32][64];
    const int tid = threadIdx.x;
    const int jb = blockIdx.x >> 2, hd = blockIdx.x & 3;
    const int n0 = jb * 32;
    const int rg = tid >> 6, cl = tid & 63;
    float acc[8];
#pragma unroll
    for (int r = 0; r < 8; ++r) acc[r] = 0.f;

    for (int kc = 0; kc < IN_F; kc += 32) {
        {   // stage h tile: 32 rows x 32 k
            const int r = tid >> 3, k4 = (tid & 7) << 2;
            *(float4*)&hs[r][k4] = *(const float4*)&h[(size_t)(n0 + r) * IN_F + kc + k4];
        }
#pragma unroll
        for (int q = 0; q < 2; ++q) {   // stage W tile: 32 k x 64 c
            const int f = tid + q * 256;
            const int k = f >> 4, c4 = (f & 15) << 2;
            *(float4*)&Ws[k][c4] = *(const float4*)&W[(size_t)(kc + k) * HO + hd * 64 + c4];
        }
        __syncthreads();
#pragma unroll
        for (int k = 0; k < 32; ++k) {
            const float wv = Ws[k][cl];
#pragma unroll
            for (int r = 0; r < 8; ++r)
                acc[r] = fmaf(hs[rg * 8 + r][k], wv, acc[r]);
        }
        __syncthreads();
    }

    // pk store: one bf16x8 fragment per thread (kb = rg, e = r)
    {
        const int g = cl >> 4, lr = cl & 15;
        unsigned short* fb = pk + ((size_t)(jb * HEADS + hd) * 4 + g) * 512;
        bf16x8 v;
#pragma unroll
        for (int r = 0; r < 8; ++r) v[r] = (short)f2bf(acc[r]);
        *(bf16x8*)(fb + (rg * 16 + lr) * 8) = v;
    }

    // fused coeffs
    const float asrc = a[hd * AVEC + cl];
    const float adst = a[hd * AVEC + OUT_F + cl];
    float s_keep = 0.f, d_keep = 0.f;
#pragma unroll
    for (int r = 0; r < 8; ++r) {
        float sp = acc[r] * asrc;
        float dp = acc[r] * adst;
#pragma unroll
        for (int off = 32; off >= 1; off >>= 1) {
            sp += __shfl_xor(sp, off);
            dp += __shfl_xor(dp, off);
        }
        if (cl == r) { s_keep = sp; d_keep = dp; }
    }
    if (cl < 8) {
        const int i = n0 + rg * 8 + cl;
        float eg = 0.f;
        const float* erow = edge_attr + (size_t)i * EDGE_F;
#pragma unroll
        for (int e4 = 0; e4 < EDGE_F; e4 += 4) {
            const float4 ev = *(const float4*)(erow + e4);
            const float4 av = *(const float4*)(a + hd * AVEC + 2 * OUT_F + e4);
            eg = fmaf(ev.x, av.x, fmaf(ev.y, av.y, fmaf(ev.z, av.z, fmaf(ev.w, av.w, eg))));
        }
        src[i * HEADS + hd] = s_keep * LOG2E;                  // pre-scaled for exp2
        cdpT[(size_t)hd * NN + i] = (d_keep + eg) * LOG2E;
    }
}

// ---- kernel 3: PV via MFMA; 16 rows/block, 8 j-slice waves, 4 blocks/CU ----
// block = (ib, hd): rows i0=ib*16, head hd. wave js covers j = js*32 + k*256.
__global__ __launch_bounds__(512, 8) void k_pv(const unsigned* __restrict__ abitsT,
                                               const unsigned short* __restrict__ pk,
                                               const float* __restrict__ src,
                                               const float* __restrict__ cdpT,
                                               float* __restrict__ out) {
    __shared__ float plds[8][16][65];   // [js][row][col] partial C (33.3 KB)
    __shared__ float lsum[8][16];       // [js][row] partial L
    const int tid = threadIdx.x;
    const int js = tid >> 6, l = tid & 63;
    const int ib = blockIdx.x >> 2, hd = blockIdx.x & 3;
    const int i0 = ib * 16;
    const int lr = l & 15, kb = l >> 4;
    const int i = i0 + lr;                           // this lane's A-row
    const float si = src[i * HEADS + hd];
    const float* crow = cdpT + (size_t)hd * NN + kb * 8;
    const unsigned short* pkb = pk + (size_t)hd * 2048 + l * 8;

    bf16x8 bones;
#pragma unroll
    for (int r = 0; r < 8; ++r) bones[r] = (short)0x3F80;   // bf16 1.0

    f32x4 acc0 = {0.f, 0.f, 0.f, 0.f};
    f32x4 acc1 = {0.f, 0.f, 0.f, 0.f};
    f32x4 acc2 = {0.f, 0.f, 0.f, 0.f};
    f32x4 acc3 = {0.f, 0.f, 0.f, 0.f};
    f32x4 accL = {0.f, 0.f, 0.f, 0.f};

    for (int jt = js * 32; jt < NN; jt += 256) {
        const unsigned wbits = abitsT[(size_t)(jt >> 5) * NN + i];
        const unsigned byte = (wbits >> (kb * 8)) & 0xFFu;
        const float4 c0 = *(const float4*)(crow + jt);
        const float4 c1 = *(const float4*)(crow + jt + 4);
        const unsigned short* fb = pkb + (size_t)(jt >> 5) * (HEADS * 4 * 512);
        const bf16x8 b0 = *(const bf16x8*)(fb);
        const bf16x8 b1 = *(const bf16x8*)(fb + 512);
        const bf16x8 b2 = *(const bf16x8*)(fb + 1024);
        const bf16x8 b3 = *(const bf16x8*)(fb + 1536);
        float e, p0, p1, p2, p3, p4, p5, p6, p7;
        e = si + c0.x; e = fmaxf(e, ALPHA * e); e = (byte &   1u) ? e : 0.f; p0 = exp2fast(e);
        e = si + c0.y; e = fmaxf(e, ALPHA * e); e = (byte &   2u) ? e : 0.f; p1 = exp2fast(e);
        e = si + c0.z; e = fmaxf(e, ALPHA * e); e = (byte &   4u) ? e : 0.f; p2 = exp2fast(e);
        e = si + c0.w; e = fmaxf(e, ALPHA * e); e = (byte &   8u) ? e : 0.f; p3 = exp2fast(e);
        e = si + c1.x; e = fmaxf(e, ALPHA * e); e = (byte &  16u) ? e : 0.f; p4 = exp2fast(e);
        e = si + c1.y; e = fmaxf(e, ALPHA * e); e = (byte &  32u) ? e : 0.f; p5 = exp2fast(e);
        e = si + c1.z; e = fmaxf(e, ALPHA * e); e = (byte &  64u) ? e : 0.f; p6 = exp2fast(e);
        e = si + c1.w; e = fmaxf(e, ALPHA * e); e = (byte & 128u) ? e : 0.f; p7 = exp2fast(e);
        bf16x8 af;
        af[0] = (short)f2bf(p0); af[1] = (short)f2bf(p1);
        af[2] = (short)f2bf(p2); af[3] = (short)f2bf(p3);
        af[4] = (short)f2bf(p4); af[5] = (short)f2bf(p5);
        af[6] = (short)f2bf(p6); af[7] = (short)f2bf(p7);
        acc0 = __builtin_amdgcn_mfma_f32_16x16x32_bf16(af, b0, acc0, 0, 0, 0);
        acc1 = __builtin_amdgcn_mfma_f32_16x16x32_bf16(af, b1, acc1, 0, 0, 0);
        acc2 = __builtin_amdgcn_mfma_f32_16x16x32_bf16(af, b2, acc2, 0, 0, 0);
        acc3 = __builtin_amdgcn_mfma_f32_16x16x32_bf16(af, b3, acc3, 0, 0, 0);
        accL = __builtin_amdgcn_mfma_f32_16x16x32_bf16(af, bones, accL, 0, 0, 0);
    }

    // L partials: accL[r] = row-sum for row kb*4+r
    if (lr == 0) {
#pragma unroll
        for (int r = 0; r < 4; ++r)
            lsum[js][kb * 4 + r] = accL[r];
    }
    // C partials: row = kb*4+r, col = g*16+lr
#pragma unroll
    for (int r = 0; r < 4; ++r) {
        const int row = kb * 4 + r;
        plds[js][row][ 0 + lr] = acc0[r];
        plds[js][row][16 + lr] = acc1[r];
        plds[js][row][32 + lr] = acc2[r];
        plds[js][row][48 + lr] = acc3[r];
    }
    __syncthreads();

    // cross-wave reduce + divide + ELU + store (1024 elems, 2 per thread)
    const int row = tid >> 5, cp = (tid & 31) * 2;
    float L = 0.f, x0 = 0.f, x1 = 0.f;
#pragma unroll
    for (int p = 0; p < 8; ++p) {
        L  += lsum[p][row];
        x0 += plds[p][row][cp];
        x1 += plds[p][row][cp + 1];
    }
    const float inv = 1.f / L;
    float2 o;
    float x;
    x = x0 * inv; o.x = x > 0.f ? x : (__expf(x) - 1.f);
    x = x1 * inv; o.y = x > 0.f ? x : (__expf(x) - 1.f);
    *(float2*)(out + (size_t)(i0 + row) * HO + hd * 64 + cp) = o;
}

extern "C" void kernel_launch(void* const* d_in, const int* in_sizes, int n_in,
                              void* d_out, int out_size, void* d_ws, size_t ws_size,
                              hipStream_t stream) {
    const float* h         = (const float*)d_in[0];
    const int*   adj       = (const int*)d_in[1];
    const float* edge_attr = (const float*)d_in[2];
    const float* W         = (const float*)d_in[3];
    const float* a         = (const float*)d_in[4];
    float* out = (float*)d_out;

    unsigned short* pk     = (unsigned short*)d_ws;                 // NN*HO bf16 (2 MB)
    float*          cdpT   = (float*)(pk + (size_t)NN * HO);        // HEADS*NN f32
    float*          src    = cdpT + (size_t)HEADS * NN;             // NN*HEADS f32
    unsigned*       abitsT = (unsigned*)(src + (size_t)NN * HEADS); // NN*NN/32 (2 MB)

    k_pack<<<256 * 4, 256, 0, stream>>>(adj, abitsT);
    k_wh<<<128 * HEADS, 256, 0, stream>>>(h, W, a, edge_attr, pk, src, cdpT);
    k_pv<<<256 * 4, 512, 0, stream>>>(abitsT, pk, src, cdpT, out);
}